// Round 7
// baseline (523.490 us; speedup 1.0000x reference)
//
#include <hip/hip_runtime.h>
#include <cstdint>

typedef unsigned short u16;
typedef u16 u16x8 __attribute__((ext_vector_type(8)));
typedef __bf16 bf16x8 __attribute__((ext_vector_type(8)));
typedef float f32x4 __attribute__((ext_vector_type(4)));

#define DEV static __device__ __forceinline__

// problem constants
constexpr int NT = 8192;         // tokens
constexpr int NP = NT * 2;       // 16384 (token, k) pairs
constexpr int NE = 8;
constexpr int DM = 1024;
constexpr int DF = 2048;
constexpr int MAXS = 17408;      // >= 16384 + 8*127 alignment slack
constexpr int MAXTILES = 136;    // >= 128 + 7

DEV u16 f2bf(float f) {          // RTNE float -> bf16 bits
  uint32_t u = __builtin_bit_cast(uint32_t, f);
  u += 0x7fffu + ((u >> 16) & 1u);
  return (u16)(u >> 16);
}

DEV void gload16(const void* g, void* l) {
  __builtin_amdgcn_global_load_lds((const __attribute__((address_space(1))) void*)g,
                                   (__attribute__((address_space(3))) void*)l, 16, 0, 0);
}

DEV bf16x8 ldfrag(const char* p) { return __builtin_bit_cast(bf16x8, *(const u16x8*)p); }

// ---- routing ----
// meta[0..7]=counts, [8..15]=cursor, [16..23]=padded offsets, [24]=total rows,
// [25]=num tiles, [32..32+MAXTILES)=tile table (expert | mtile<<8)
__global__ void k_init(int* meta, int* slot_token) {
  const int i = blockIdx.x * 256 + threadIdx.x;
  if (i < 32) meta[i] = 0;
  if (i < MAXS) slot_token[i] = -1;
}

__global__ void k_count(const int* __restrict__ eidx, int* meta) {
  const int p = blockIdx.x * 256 + threadIdx.x;
  if (p < NP) atomicAdd(&meta[eidx[p] & 7], 1);
}

__global__ void k_scan(int* meta) {
  if (threadIdx.x == 0 && blockIdx.x == 0) {
    int off = 0, ti = 0;
    for (int e = 0; e < NE; ++e) {
      meta[16 + e] = off;
      const int c = meta[e];
      off += ((c + 127) >> 7) << 7;
      for (int mt = 0; mt * 128 < c; ++mt) meta[32 + ti++] = e | (mt << 8);
    }
    meta[24] = off;
    meta[25] = ti;
  }
}

__global__ void k_fill(const int* __restrict__ eidx, const float* __restrict__ ew,
                       int* meta, int* slot_token, float* slot_weight, int* pair_slot) {
  const int p = blockIdx.x * 256 + threadIdx.x;
  if (p < NP) {
    const int e = eidx[p] & 7;
    const int pos = meta[16 + e] + atomicAdd(&meta[8 + e], 1);
    slot_token[pos]  = p >> 1;
    slot_weight[pos] = ew[p];
    pair_slot[p] = pos;
  }
}

// gather selected token rows -> bf16, zeros for padding slots
__global__ void k_gather(const float* __restrict__ x, const int* __restrict__ slot_token,
                         u16* __restrict__ Xg) {
  const int s = blockIdx.x;
  const int tok = slot_token[s];
  const int c = threadIdx.x * 4;
  alignas(8) u16 b[4] = {0, 0, 0, 0};
  if (tok >= 0) {
    const float4 v = *reinterpret_cast<const float4*>(x + (size_t)tok * DM + c);
    b[0] = f2bf(v.x); b[1] = f2bf(v.y); b[2] = f2bf(v.z); b[3] = f2bf(v.w);
  }
  *reinterpret_cast<uint2*>(Xg + (size_t)s * DM + c) = *reinterpret_cast<const uint2*>(b);
}

// src [K][N] fp32 -> dst [N][K] bf16
__global__ void k_transpose(const float* __restrict__ src, u16* __restrict__ dst, int K, int N) {
  const size_t mo = (size_t)blockIdx.z * K * N;
  const float* s = src + mo;
  u16* d = dst + mo;
  const int n0 = blockIdx.x * 64, k0 = blockIdx.y * 64;
  __shared__ u16 tile[64][72];
  const int t = threadIdx.x;
  const int r = t >> 4, cb = (t & 15) * 4;
#pragma unroll
  for (int it = 0; it < 4; ++it) {
    const float4 v = *reinterpret_cast<const float4*>(s + (size_t)(k0 + r + it * 16) * N + n0 + cb);
    tile[r + it * 16][cb + 0] = f2bf(v.x);
    tile[r + it * 16][cb + 1] = f2bf(v.y);
    tile[r + it * 16][cb + 2] = f2bf(v.z);
    tile[r + it * 16][cb + 3] = f2bf(v.w);
  }
  __syncthreads();
  const int nl = t >> 2, ks = (t & 3) * 16;
  alignas(16) u16 vals[16];
#pragma unroll
  for (int j = 0; j < 16; ++j) vals[j] = tile[ks + j][nl];
  u16* dp = d + (size_t)(n0 + nl) * K + k0 + ks;
  *reinterpret_cast<uint4*>(dp)     = *reinterpret_cast<const uint4*>(vals);
  *reinterpret_cast<uint4*>(dp + 8) = *reinterpret_cast<const uint4*>(vals + 8);
}

// GEMM1: H = silu(Xg @ w1^T') * (Xg @ w2^T')
// tile 128x64 dual, BK=32, 4 waves, per-wave 64x32 dual (acc 64)   [R4 tile]
// 2-buffer, read-then-restage, counted vmcnt(4): prefetch never drains
__global__ __launch_bounds__(256, 3)
void k_gemm1(const u16* __restrict__ Xg, const u16* __restrict__ w1T, const u16* __restrict__ w2T,
             u16* __restrict__ H, const int* __restrict__ meta) {
  const int ti = blockIdx.y;
  if (ti >= meta[25]) return;
  const int ent = meta[32 + ti];
  const int e = ent & 255, mt = ent >> 8;
  const int base = meta[16 + e];
  const int n0 = blockIdx.x * 64;

  // per buffer (16KB): A[128][64B] @0 | B1[64][64B] @8192 | B2[64][64B] @12288
  __shared__ __align__(16) char sm[2][16384];

  const int tid = threadIdx.x;
  const int lane = tid & 63;
  const int w = tid >> 6;
  const int wr = w >> 1, wc = w & 1;
  const int lrow = lane & 15, lk = lane >> 4;
  const int srow = tid >> 2;
  const int scol = (tid & 3) * 16;

  const char* Ag  = (const char*)(Xg + (size_t)(base + mt * 128) * DM);
  const char* B1g = (const char*)(w1T + ((size_t)e * DF + n0) * DM);
  const char* B2g = (const char*)(w2T + ((size_t)e * DF + n0) * DM);

  f32x4 acc1[4][2] = {};
  f32x4 acc2[4][2] = {};

  auto STAGE = [&](char* s, int k0) {          // 4 x gload16 per thread (per wave: 4 VMEM)
    const size_t kb = (size_t)k0 * 2;
    gload16(Ag  + (size_t)srow * 2048 + kb + scol,        s + w * 1024);
    gload16(Ag  + (size_t)(srow + 64) * 2048 + kb + scol, s + 4096 + w * 1024);
    gload16(B1g + (size_t)srow * 2048 + kb + scol,        s + 8192 + w * 1024);
    gload16(B2g + (size_t)srow * 2048 + kb + scol,        s + 12288 + w * 1024);
  };

  STAGE(sm[0], 0);     // tile 0
  STAGE(sm[1], 32);    // tile 1

  for (int t = 0; t < 32; ++t) {
    // tile t landed (issued 2 steps ago); tile t+1's 4 loads stay in flight
    asm volatile("s_waitcnt vmcnt(4)" ::: "memory");
    __builtin_amdgcn_s_barrier();            // all waves' tile-t chunks landed
    const char* s = sm[t & 1];

    bf16x8 a[4], b1[2], b2[2];
#pragma unroll
    for (int m = 0; m < 4; ++m)
      a[m] = ldfrag(s + (wr * 64 + m * 16 + lrow) * 64 + lk * 16);
#pragma unroll
    for (int n = 0; n < 2; ++n) {
      b1[n] = ldfrag(s + 8192  + (wc * 32 + n * 16 + lrow) * 64 + lk * 16);
      b2[n] = ldfrag(s + 12288 + (wc * 32 + n * 16 + lrow) * 64 + lk * 16);
    }
#pragma unroll
    for (int m = 0; m < 4; ++m)
#pragma unroll
      for (int n = 0; n < 2; ++n) {
        acc1[m][n] = __builtin_amdgcn_mfma_f32_16x16x32_bf16(a[m], b1[n], acc1[m][n], 0, 0, 0);
        acc2[m][n] = __builtin_amdgcn_mfma_f32_16x16x32_bf16(a[m], b2[n], acc2[m][n], 0, 0, 0);
      }
    __builtin_amdgcn_s_barrier();            // all waves done reading buf[t&1]
    int kn = (t + 2) * 32; if (kn > DM - 32) kn = DM - 32;   // dummy refill at tail
    STAGE(sm[t & 1], kn);                    // restage freed buffer with tile t+2
  }

  u16* Hrow = H + (size_t)(base + mt * 128) * DF + n0;
#pragma unroll
  for (int m = 0; m < 4; ++m)
#pragma unroll
    for (int r = 0; r < 4; ++r) {
      const int rl = wr * 64 + m * 16 + lk * 4 + r;
      u16* hp = Hrow + (size_t)rl * DF + wc * 32 + lrow;
#pragma unroll
      for (int n = 0; n < 2; ++n) {
        const float h1 = acc1[m][n][r], h2 = acc2[m][n][r];
        const float sv = h1 / (1.f + __expf(-h1)) * h2;   // silu(h1)*h2
        hp[n * 16] = f2bf(sv);
      }
    }
}

// GEMM2: O_slot[slot] = wgt * (H @ w3^T')   -- plain stores, no atomics
// tile 128x128, BK=32, 4 waves (2x2), per-wave 64x64 (acc 64)   [R4 tile]
// 2-buffer, read-then-restage, counted vmcnt(4)
__global__ __launch_bounds__(256, 3)
void k_gemm2(const u16* __restrict__ H, const u16* __restrict__ w3T, const int* __restrict__ meta,
             const float* __restrict__ slot_weight, u16* __restrict__ O) {
  const int ti = blockIdx.y;
  if (ti >= meta[25]) return;
  const int ent = meta[32 + ti];
  const int e = ent & 255, mt = ent >> 8;
  const int base = meta[16 + e];
  const int n0 = blockIdx.x * 128;

  // per buffer (16KB): A[128][64B] @0 | B[128][64B] @8192
  __shared__ __align__(16) char sm[2][16384];

  const int tid = threadIdx.x;
  const int lane = tid & 63;
  const int w = tid >> 6;
  const int wr = w >> 1, wc = w & 1;
  const int lrow = lane & 15, lk = lane >> 4;
  const int srow = tid >> 2;
  const int scol = (tid & 3) * 16;

  const char* Ag = (const char*)(H + (size_t)(base + mt * 128) * DF);
  const char* Bg = (const char*)(w3T + ((size_t)e * DM + n0) * DF);

  f32x4 acc[4][4] = {};

  auto STAGE = [&](char* s, int k0) {          // 4 x gload16 per thread
    const size_t kb = (size_t)k0 * 2;
    gload16(Ag + (size_t)srow * 4096 + kb + scol,        s + w * 1024);
    gload16(Ag + (size_t)(srow + 64) * 4096 + kb + scol, s + 4096 + w * 1024);
    gload16(Bg + (size_t)srow * 4096 + kb + scol,        s + 8192 + w * 1024);
    gload16(Bg + (size_t)(srow + 64) * 4096 + kb + scol, s + 12288 + w * 1024);
  };

  STAGE(sm[0], 0);
  STAGE(sm[1], 32);

  for (int t = 0; t < 64; ++t) {
    asm volatile("s_waitcnt vmcnt(4)" ::: "memory");
    __builtin_amdgcn_s_barrier();
    const char* s = sm[t & 1];

    bf16x8 a[4], b[4];
#pragma unroll
    for (int m = 0; m < 4; ++m)
      a[m] = ldfrag(s + (wr * 64 + m * 16 + lrow) * 64 + lk * 16);
#pragma unroll
    for (int n = 0; n < 4; ++n)
      b[n] = ldfrag(s + 8192 + (wc * 64 + n * 16 + lrow) * 64 + lk * 16);
#pragma unroll
    for (int m = 0; m < 4; ++m)
#pragma unroll
      for (int n = 0; n < 4; ++n)
        acc[m][n] = __builtin_amdgcn_mfma_f32_16x16x32_bf16(a[m], b[n], acc[m][n], 0, 0, 0);
    __builtin_amdgcn_s_barrier();
    int kn = (t + 2) * 32; if (kn > DF - 32) kn = DF - 32;
    STAGE(sm[t & 1], kn);
  }

  const int sb = base + mt * 128;
#pragma unroll
  for (int m = 0; m < 4; ++m)
#pragma unroll
    for (int r = 0; r < 4; ++r) {
      const int rl = wr * 64 + m * 16 + lk * 4 + r;
      const float wgt = slot_weight[sb + rl];
      u16* op = O + (size_t)(sb + rl) * DM + n0 + wc * 64 + lrow;
#pragma unroll
      for (int n = 0; n < 4; ++n)
        op[n * 16] = f2bf(wgt * acc[m][n][r]);
    }
}

// out[t] = O[slot(2t)] + O[slot(2t+1)]
__global__ void k_combine(const u16* __restrict__ O, const int* __restrict__ pair_slot,
                          float* __restrict__ out) {
  const int t = blockIdx.x;
  const int c = threadIdx.x * 4;
  const int sa = pair_slot[2 * t], sb = pair_slot[2 * t + 1];
  const uint2 va = *reinterpret_cast<const uint2*>(O + (size_t)sa * DM + c);
  const uint2 vb = *reinterpret_cast<const uint2*>(O + (size_t)sb * DM + c);
  float4 r;
  r.x = __builtin_bit_cast(float, va.x << 16)          + __builtin_bit_cast(float, vb.x << 16);
  r.y = __builtin_bit_cast(float, va.x & 0xffff0000u)  + __builtin_bit_cast(float, vb.x & 0xffff0000u);
  r.z = __builtin_bit_cast(float, va.y << 16)          + __builtin_bit_cast(float, vb.y << 16);
  r.w = __builtin_bit_cast(float, va.y & 0xffff0000u)  + __builtin_bit_cast(float, vb.y & 0xffff0000u);
  *reinterpret_cast<float4*>(out + (size_t)t * DM + c) = r;
}

extern "C" void kernel_launch(void* const* d_in, const int* in_sizes, int n_in,
                              void* d_out, int out_size, void* d_ws, size_t ws_size,
                              hipStream_t stream) {
  const float* x  = (const float*)d_in[0];
  const int* eidx = (const int*)d_in[1];
  const float* ew = (const float*)d_in[2];
  const float* w1 = (const float*)d_in[3];
  const float* w2 = (const float*)d_in[4];
  const float* w3 = (const float*)d_in[5];
  float* out = (float*)d_out;
  char* ws = (char*)d_ws;

  int* meta          = (int*)ws;                           // 1 KB
  int* pair_slot     = (int*)(ws + 1024);                  // NP*4 = 64 KB
  int* slot_token    = (int*)(ws + 1024 + 65536);
  float* slot_weight = (float*)(ws + 1024 + 65536 + (size_t)MAXS * 4);
  size_t off = 1024 + 65536 + (size_t)MAXS * 8;
  u16* Xg  = (u16*)(ws + off); off += (size_t)MAXS * DM * 2;   // reused as O_slot
  u16* w1T = (u16*)(ws + off); off += (size_t)NE * DM * DF * 2;
  u16* w2T = (u16*)(ws + off); off += (size_t)NE * DM * DF * 2;
  u16* w3T = (u16*)(ws + off); off += (size_t)NE * DM * DF * 2;
  u16* H   = (u16*)(ws + off);  // MAXS * DF * 2 bytes
  u16* O   = Xg;                // Xg is dead after k_gemm1

  k_init<<<(MAXS + 255) / 256, 256, 0, stream>>>(meta, slot_token);
  k_count<<<NP / 256, 256, 0, stream>>>(eidx, meta);
  k_scan<<<1, 64, 0, stream>>>(meta);
  k_fill<<<NP / 256, 256, 0, stream>>>(eidx, ew, meta, slot_token, slot_weight, pair_slot);
  k_gather<<<MAXS, 256, 0, stream>>>(x, slot_token, Xg);
  k_transpose<<<dim3(DF / 64, DM / 64, NE), 256, 0, stream>>>(w1, w1T, DM, DF);
  k_transpose<<<dim3(DF / 64, DM / 64, NE), 256, 0, stream>>>(w2, w2T, DM, DF);
  k_transpose<<<dim3(DM / 64, DF / 64, NE), 256, 0, stream>>>(w3, w3T, DF, DM);
  k_gemm1<<<dim3(DF / 64, MAXTILES, 1), 256, 0, stream>>>(Xg, w1T, w2T, H, meta);
  k_gemm2<<<dim3(DM / 128, MAXTILES, 1), 256, 0, stream>>>(H, w3T, meta, slot_weight, O);
  k_combine<<<NT, 256, 0, stream>>>(O, pair_slot, out);
}

// Round 8
// 519.310 us; speedup vs baseline: 1.0080x; 1.0080x over previous
//
#include <hip/hip_runtime.h>
#include <cstdint>

typedef unsigned short u16;
typedef u16 u16x8 __attribute__((ext_vector_type(8)));
typedef __bf16 bf16x8 __attribute__((ext_vector_type(8)));
typedef float f32x4 __attribute__((ext_vector_type(4)));

#define DEV static __device__ __forceinline__

// problem constants
constexpr int NT = 8192;         // tokens
constexpr int NP = NT * 2;       // 16384 (token, k) pairs
constexpr int NE = 8;
constexpr int DM = 1024;
constexpr int DF = 2048;
constexpr int MAXS = 17664;      // 16384 + 8*127 pad + 256-tile overhang
constexpr int MAXT256 = 71;      // sum ceil(cnt/256) <= 64 + 7

DEV u16 f2bf(float f) {          // RTNE float -> bf16 bits
  uint32_t u = __builtin_bit_cast(uint32_t, f);
  u += 0x7fffu + ((u >> 16) & 1u);
  return (u16)(u >> 16);
}

DEV void gload16(const void* g, void* l) {
  __builtin_amdgcn_global_load_lds((const __attribute__((address_space(1))) void*)g,
                                   (__attribute__((address_space(3))) void*)l, 16, 0, 0);
}

DEV bf16x8 ldfrag(const char* p) { return __builtin_bit_cast(bf16x8, *(const u16x8*)p); }

DEV f32x4 MFMA(bf16x8 a, bf16x8 b, f32x4 c) {
  return __builtin_amdgcn_mfma_f32_16x16x32_bf16(a, b, c, 0, 0, 0);
}

// ---- routing ----
// meta[0..7]=counts, [8..15]=cursor, [16..23]=padded offsets, [24]=total rows,
// [25]=n tiles256, [32..103)=tile table (expert | mtile<<8)
__global__ void k_init(int* meta, int* slot_token) {
  const int i = blockIdx.x * 256 + threadIdx.x;
  if (i < 32) meta[i] = 0;
  if (i < MAXS) slot_token[i] = -1;
}

__global__ void k_count(const int* __restrict__ eidx, int* meta) {
  const int p = blockIdx.x * 256 + threadIdx.x;
  if (p < NP) atomicAdd(&meta[eidx[p] & 7], 1);
}

__global__ void k_scan(int* meta) {
  if (threadIdx.x == 0 && blockIdx.x == 0) {
    int off = 0, t2 = 0;
    for (int e = 0; e < NE; ++e) {
      meta[16 + e] = off;
      const int c = meta[e];
      off += ((c + 127) >> 7) << 7;
      for (int mt = 0; mt * 256 < c; ++mt) meta[32 + t2++] = e | (mt << 8);
    }
    meta[24] = off;
    meta[25] = t2;
  }
}

__global__ void k_fill(const int* __restrict__ eidx, const float* __restrict__ ew,
                       int* meta, int* slot_token, float* slot_weight, int* pair_slot) {
  const int p = blockIdx.x * 256 + threadIdx.x;
  if (p < NP) {
    const int e = eidx[p] & 7;
    const int pos = meta[16 + e] + atomicAdd(&meta[8 + e], 1);
    slot_token[pos]  = p >> 1;
    slot_weight[pos] = ew[p];
    pair_slot[p] = pos;
  }
}

// gather selected token rows -> bf16, zeros for padding/slack slots
__global__ void k_gather(const float* __restrict__ x, const int* __restrict__ slot_token,
                         u16* __restrict__ Xg) {
  const int s = blockIdx.x;
  const int tok = slot_token[s];
  const int c = threadIdx.x * 4;
  alignas(8) u16 b[4] = {0, 0, 0, 0};
  if (tok >= 0) {
    const float4 v = *reinterpret_cast<const float4*>(x + (size_t)tok * DM + c);
    b[0] = f2bf(v.x); b[1] = f2bf(v.y); b[2] = f2bf(v.z); b[3] = f2bf(v.w);
  }
  *reinterpret_cast<uint2*>(Xg + (size_t)s * DM + c) = *reinterpret_cast<const uint2*>(b);
}

// src [K][N] fp32 -> dst [N][K] bf16
__global__ void k_transpose(const float* __restrict__ src, u16* __restrict__ dst, int K, int N) {
  const size_t mo = (size_t)blockIdx.z * K * N;
  const float* s = src + mo;
  u16* d = dst + mo;
  const int n0 = blockIdx.x * 64, k0 = blockIdx.y * 64;
  __shared__ u16 tile[64][72];
  const int t = threadIdx.x;
  const int r = t >> 4, cb = (t & 15) * 4;
#pragma unroll
  for (int it = 0; it < 4; ++it) {
    const float4 v = *reinterpret_cast<const float4*>(s + (size_t)(k0 + r + it * 16) * N + n0 + cb);
    tile[r + it * 16][cb + 0] = f2bf(v.x);
    tile[r + it * 16][cb + 1] = f2bf(v.y);
    tile[r + it * 16][cb + 2] = f2bf(v.z);
    tile[r + it * 16][cb + 3] = f2bf(v.w);
  }
  __syncthreads();
  const int nl = t >> 2, ks = (t & 3) * 16;
  alignas(16) u16 vals[16];
#pragma unroll
  for (int j = 0; j < 16; ++j) vals[j] = tile[ks + j][nl];
  u16* dp = d + (size_t)(n0 + nl) * K + k0 + ks;
  *reinterpret_cast<uint4*>(dp)     = *reinterpret_cast<const uint4*>(vals);
  *reinterpret_cast<uint4*>(dp + 8) = *reinterpret_cast<const uint4*>(vals + 8);
}

// ============ 8-phase GEMM1: H = silu(Xg@w1T) * (Xg@w2T) ============
// BM=256, BN=128 dual (effective 256^2), BK=64, 8 waves (2Mx4N), acc 128
// LDS 2 x 64KB: A[256][64k] @0 | B1[128][64k] @32768 | B2 @49152
// XOR swizzle col16 ^= row&7 (pre-swizzled staging source, swizzled read)
__global__ __launch_bounds__(512, 2)
void k_gemm1(const u16* __restrict__ Xg, const u16* __restrict__ w1T, const u16* __restrict__ w2T,
             u16* __restrict__ H, const int* __restrict__ meta) {
  const int ti = blockIdx.y;
  if (ti >= meta[25]) return;
  const int ent = meta[32 + ti];
  const int e = ent & 255, mt = ent >> 8;
  const int base = meta[16 + e];
  const int cntp = meta[17 + e] - base;   // this expert's 128-padded row count
  const int n0 = blockIdx.x * 128;

  __shared__ __align__(16) char sm[2][65536];

  const int tid = threadIdx.x;
  const int lane = tid & 63;
  const int w = tid >> 6;                  // 0..7
  const int wr = w >> 2, wc = w & 3;       // 2M x 4N
  const int lrow = lane & 15, lk = lane >> 4;
  const int SX = lrow & 7;
  int cofs[2];
  cofs[0] = ((0 * 4 + lk) ^ SX) * 16;
  cofs[1] = ((1 * 4 + lk) ^ SX) * 16;
  const int Abase  = (wr * 128 + lrow) * 128;
  const int B1base = 32768 + (wc * 32 + lrow) * 128;
  const int B2base = B1base + 16384;

  // staging: thread t -> LDS linear (row = rnd*64 + t>>3, slot16 = t&7)
  const int srow8 = tid >> 3;
  const int scolw = ((tid & 7) ^ (srow8 & 7)) * 16;   // pre-swizzled source col

  const char* AgT  = (const char*)(Xg + (size_t)(base + mt * 256) * DM) + (size_t)srow8 * 2048 + scolw;
  const char* B1T  = (const char*)(w1T + ((size_t)e * DF + n0) * DM)    + (size_t)srow8 * 2048 + scolw;
  const char* B2T  = (const char*)(w2T + ((size_t)e * DF + n0) * DM)    + (size_t)srow8 * 2048 + scolw;

  f32x4 acc1[8][2] = {};
  f32x4 acc2[8][2] = {};

  // stage pair q (2 x gload16) of one K-tile into buffer d
  auto SP = [&](char* d, size_t kb, int q) {
    switch (q) {
      case 0: gload16(AgT + kb,          d + tid * 16);
              gload16(AgT + 131072 + kb, d + 8192  + tid * 16); break;
      case 1: gload16(AgT + 262144 + kb, d + 16384 + tid * 16);
              gload16(AgT + 393216 + kb, d + 24576 + tid * 16); break;
      case 2: gload16(B1T + kb,          d + 32768 + tid * 16);
              gload16(B1T + 131072 + kb, d + 40960 + tid * 16); break;
      case 3: gload16(B2T + kb,          d + 49152 + tid * 16);
              gload16(B2T + 131072 + kb, d + 57344 + tid * 16); break;
    }
  };

  bf16x8 b1f[2][2], b2f[2][2];

  auto LDA4 = [&](const char* s, int mh, int ks, bf16x8* a) {
#pragma unroll
    for (int j = 0; j < 4; ++j)
      a[j] = ldfrag(s + Abase + mh * 8192 + j * 2048 + cofs[ks]);
  };
  auto MF16 = [&](int mh, int ks, const bf16x8* a) {
    __builtin_amdgcn_s_setprio(1);
#pragma unroll
    for (int j = 0; j < 4; ++j)
#pragma unroll
      for (int n = 0; n < 2; ++n) {
        acc1[mh * 4 + j][n] = MFMA(a[j], b1f[n][ks], acc1[mh * 4 + j][n]);
        acc2[mh * 4 + j][n] = MFMA(a[j], b2f[n][ks], acc2[mh * 4 + j][n]);
      }
    __builtin_amdgcn_s_setprio(0);
  };

  SP(sm[0], 0, 0); SP(sm[0], 0, 1); SP(sm[0], 0, 2); SP(sm[0], 0, 3);   // tile 0

  for (int kt = 0; kt < 16; ++kt) {
    const char* s = sm[kt & 1];
    char* d = sm[(kt + 1) & 1];
    const size_t kbn = (size_t)((kt + 1 < 16) ? kt + 1 : 15) * 128;
    bf16x8 a[4];

    // phase 0: stage q0(next), counted wait (never drains), B-frags + A mh0 ks0
    SP(d, kbn, 0);
    asm volatile("s_waitcnt vmcnt(2)" ::: "memory");
    __builtin_amdgcn_s_barrier();
#pragma unroll
    for (int n = 0; n < 2; ++n)
#pragma unroll
      for (int s2 = 0; s2 < 2; ++s2) {
        b1f[n][s2] = ldfrag(s + B1base + n * 2048 + cofs[s2]);
        b2f[n][s2] = ldfrag(s + B2base + n * 2048 + cofs[s2]);
      }
    LDA4(s, 0, 0, a);
    MF16(0, 0, a);
    __builtin_amdgcn_s_barrier();
    // phase 1
    LDA4(s, 1, 0, a);
    SP(d, kbn, 1);
    __builtin_amdgcn_s_barrier();
    MF16(1, 0, a);
    __builtin_amdgcn_s_barrier();
    // phase 2
    LDA4(s, 0, 1, a);
    SP(d, kbn, 2);
    __builtin_amdgcn_s_barrier();
    MF16(0, 1, a);
    __builtin_amdgcn_s_barrier();
    // phase 3
    LDA4(s, 1, 1, a);
    SP(d, kbn, 3);
    __builtin_amdgcn_s_barrier();
    MF16(1, 1, a);
    __builtin_amdgcn_s_barrier();
  }

  u16* Hrow = H + (size_t)(base + mt * 256) * DF + n0;
#pragma unroll
  for (int m = 0; m < 8; ++m)
#pragma unroll
    for (int r = 0; r < 4; ++r) {
      const int rloc = wr * 128 + m * 16 + lk * 4 + r;
      if (mt * 256 + rloc >= cntp) continue;   // expert-boundary mask
      u16* hp = Hrow + (size_t)rloc * DF + wc * 32 + lrow;
#pragma unroll
      for (int n = 0; n < 2; ++n) {
        const float h1 = acc1[m][n][r], h2 = acc2[m][n][r];
        const float sv = h1 / (1.f + __expf(-h1)) * h2;   // silu(h1)*h2
        hp[n * 16] = f2bf(sv);
      }
    }
}

// ============ 8-phase GEMM2: O_slot = wgt * (H @ w3T) ============
// BM=256, BN=256, BK=64, 8 waves (2Mx4N), acc 128; LDS 2 x 64KB
__global__ __launch_bounds__(512, 2)
void k_gemm2(const u16* __restrict__ H, const u16* __restrict__ w3T, const int* __restrict__ meta,
             const float* __restrict__ slot_weight, u16* __restrict__ O) {
  const int ti = blockIdx.y;
  if (ti >= meta[25]) return;
  const int ent = meta[32 + ti];
  const int e = ent & 255, mt = ent >> 8;
  const int base = meta[16 + e];
  const int cntp = meta[17 + e] - base;
  const int n0 = blockIdx.x * 256;

  __shared__ __align__(16) char sm[2][65536];

  const int tid = threadIdx.x;
  const int lane = tid & 63;
  const int w = tid >> 6;
  const int wr = w >> 2, wc = w & 3;       // 2M x 4N (per-wave 128x64)
  const int lrow = lane & 15, lk = lane >> 4;
  const int SX = lrow & 7;
  int cofs[2];
  cofs[0] = ((0 * 4 + lk) ^ SX) * 16;
  cofs[1] = ((1 * 4 + lk) ^ SX) * 16;
  const int Abase = (wr * 128 + lrow) * 128;
  const int Bbase = 32768 + (wc * 64 + lrow) * 128;

  const int srow8 = tid >> 3;
  const int scolw = ((tid & 7) ^ (srow8 & 7)) * 16;

  const char* AgT = (const char*)(H + (size_t)(base + mt * 256) * DF) + (size_t)srow8 * 4096 + scolw;
  const char* BgT = (const char*)(w3T + ((size_t)e * DM + n0) * DF)   + (size_t)srow8 * 4096 + scolw;

  f32x4 acc[8][4] = {};

  auto SP = [&](char* d, size_t kb, int q) {
    switch (q) {
      case 0: gload16(AgT + kb,          d + tid * 16);
              gload16(AgT + 262144 + kb, d + 8192  + tid * 16); break;
      case 1: gload16(AgT + 524288 + kb, d + 16384 + tid * 16);
              gload16(AgT + 786432 + kb, d + 24576 + tid * 16); break;
      case 2: gload16(BgT + kb,          d + 32768 + tid * 16);
              gload16(BgT + 262144 + kb, d + 40960 + tid * 16); break;
      case 3: gload16(BgT + 524288 + kb, d + 49152 + tid * 16);
              gload16(BgT + 786432 + kb, d + 57344 + tid * 16); break;
    }
  };

  bf16x8 bf[4][2];

  auto LDA4 = [&](const char* s, int mh, int ks, bf16x8* a) {
#pragma unroll
    for (int j = 0; j < 4; ++j)
      a[j] = ldfrag(s + Abase + mh * 8192 + j * 2048 + cofs[ks]);
  };
  auto MF16 = [&](int mh, int ks, const bf16x8* a) {
    __builtin_amdgcn_s_setprio(1);
#pragma unroll
    for (int j = 0; j < 4; ++j)
#pragma unroll
      for (int n = 0; n < 4; ++n)
        acc[mh * 4 + j][n] = MFMA(a[j], bf[n][ks], acc[mh * 4 + j][n]);
    __builtin_amdgcn_s_setprio(0);
  };

  SP(sm[0], 0, 0); SP(sm[0], 0, 1); SP(sm[0], 0, 2); SP(sm[0], 0, 3);

  for (int kt = 0; kt < 32; ++kt) {
    const char* s = sm[kt & 1];
    char* d = sm[(kt + 1) & 1];
    const size_t kbn = (size_t)((kt + 1 < 32) ? kt + 1 : 31) * 128;
    bf16x8 a[4];

    SP(d, kbn, 0);
    asm volatile("s_waitcnt vmcnt(2)" ::: "memory");
    __builtin_amdgcn_s_barrier();
#pragma unroll
    for (int n = 0; n < 4; ++n)
#pragma unroll
      for (int s2 = 0; s2 < 2; ++s2)
        bf[n][s2] = ldfrag(s + Bbase + n * 2048 + cofs[s2]);
    LDA4(s, 0, 0, a);
    MF16(0, 0, a);
    __builtin_amdgcn_s_barrier();

    LDA4(s, 1, 0, a);
    SP(d, kbn, 1);
    __builtin_amdgcn_s_barrier();
    MF16(1, 0, a);
    __builtin_amdgcn_s_barrier();

    LDA4(s, 0, 1, a);
    SP(d, kbn, 2);
    __builtin_amdgcn_s_barrier();
    MF16(0, 1, a);
    __builtin_amdgcn_s_barrier();

    LDA4(s, 1, 1, a);
    SP(d, kbn, 3);
    __builtin_amdgcn_s_barrier();
    MF16(1, 1, a);
    __builtin_amdgcn_s_barrier();
  }

  const int sb = base + mt * 256;
#pragma unroll
  for (int m = 0; m < 8; ++m)
#pragma unroll
    for (int r = 0; r < 4; ++r) {
      const int rloc = wr * 128 + m * 16 + lk * 4 + r;
      if (mt * 256 + rloc >= cntp) continue;
      const float wgt = slot_weight[sb + rloc];
      u16* op = O + (size_t)(sb + rloc) * DM + n0 + wc * 64 + lrow;
#pragma unroll
      for (int n = 0; n < 4; ++n)
        op[n * 16] = f2bf(wgt * acc[m][n][r]);
    }
}

// out[t] = O[slot(2t)] + O[slot(2t+1)]
__global__ void k_combine(const u16* __restrict__ O, const int* __restrict__ pair_slot,
                          float* __restrict__ out) {
  const int t = blockIdx.x;
  const int c = threadIdx.x * 4;
  const int sa = pair_slot[2 * t], sb = pair_slot[2 * t + 1];
  const uint2 va = *reinterpret_cast<const uint2*>(O + (size_t)sa * DM + c);
  const uint2 vb = *reinterpret_cast<const uint2*>(O + (size_t)sb * DM + c);
  float4 r;
  r.x = __builtin_bit_cast(float, va.x << 16)          + __builtin_bit_cast(float, vb.x << 16);
  r.y = __builtin_bit_cast(float, va.x & 0xffff0000u)  + __builtin_bit_cast(float, vb.x & 0xffff0000u);
  r.z = __builtin_bit_cast(float, va.y << 16)          + __builtin_bit_cast(float, vb.y << 16);
  r.w = __builtin_bit_cast(float, va.y & 0xffff0000u)  + __builtin_bit_cast(float, vb.y & 0xffff0000u);
  *reinterpret_cast<float4*>(out + (size_t)t * DM + c) = r;
}

extern "C" void kernel_launch(void* const* d_in, const int* in_sizes, int n_in,
                              void* d_out, int out_size, void* d_ws, size_t ws_size,
                              hipStream_t stream) {
  const float* x  = (const float*)d_in[0];
  const int* eidx = (const int*)d_in[1];
  const float* ew = (const float*)d_in[2];
  const float* w1 = (const float*)d_in[3];
  const float* w2 = (const float*)d_in[4];
  const float* w3 = (const float*)d_in[5];
  float* out = (float*)d_out;
  char* ws = (char*)d_ws;

  int* meta          = (int*)ws;                           // 1 KB
  int* pair_slot     = (int*)(ws + 1024);                  // 64 KB
  int* slot_token    = (int*)(ws + 1024 + 65536);
  float* slot_weight = (float*)(ws + 1024 + 65536 + (size_t)MAXS * 4);
  size_t off = 1024 + 65536 + (size_t)MAXS * 8;
  u16* Xg  = (u16*)(ws + off); off += (size_t)MAXS * DM * 2;   // reused as O_slot
  u16* w1T = (u16*)(ws + off); off += (size_t)NE * DM * DF * 2;
  u16* w2T = (u16*)(ws + off); off += (size_t)NE * DM * DF * 2;
  u16* w3T = (u16*)(ws + off); off += (size_t)NE * DM * DF * 2;
  u16* H   = (u16*)(ws + off);  // MAXS * DF * 2 bytes
  u16* O   = Xg;                // Xg is dead after k_gemm1

  k_init<<<(MAXS + 255) / 256, 256, 0, stream>>>(meta, slot_token);
  k_count<<<NP / 256, 256, 0, stream>>>(eidx, meta);
  k_scan<<<1, 64, 0, stream>>>(meta);
  k_fill<<<NP / 256, 256, 0, stream>>>(eidx, ew, meta, slot_token, slot_weight, pair_slot);
  k_gather<<<MAXS, 256, 0, stream>>>(x, slot_token, Xg);
  k_transpose<<<dim3(DF / 64, DM / 64, NE), 256, 0, stream>>>(w1, w1T, DM, DF);
  k_transpose<<<dim3(DF / 64, DM / 64, NE), 256, 0, stream>>>(w2, w2T, DM, DF);
  k_transpose<<<dim3(DM / 64, DF / 64, NE), 256, 0, stream>>>(w3, w3T, DF, DM);
  k_gemm1<<<dim3(DF / 128, MAXT256, 1), 512, 0, stream>>>(Xg, w1T, w2T, H, meta);
  k_gemm2<<<dim3(DM / 256, MAXT256, 1), 512, 0, stream>>>(H, w3T, meta, slot_weight, O);
  k_combine<<<NT, 256, 0, stream>>>(O, pair_slot, out);
}

// Round 9
// 510.587 us; speedup vs baseline: 1.0253x; 1.0171x over previous
//
#include <hip/hip_runtime.h>
#include <cstdint>

typedef unsigned short u16;
typedef u16 u16x8 __attribute__((ext_vector_type(8)));
typedef __bf16 bf16x8 __attribute__((ext_vector_type(8)));
typedef float f32x4 __attribute__((ext_vector_type(4)));

#define DEV static __device__ __forceinline__

// problem constants
constexpr int NT = 8192;         // tokens
constexpr int NP = NT * 2;       // 16384 (token, k) pairs
constexpr int NE = 8;
constexpr int DM = 1024;
constexpr int DF = 2048;
constexpr int MAXS = 17664;      // 16384 + 8*127 pad + 256-tile overhang
constexpr int MAXT256 = 71;      // sum ceil(cnt/256) <= 64 + 7
constexpr int NWG1 = 16 * MAXT256;   // 1136 (divisible by 8: chunk 142)
constexpr int NWG2 = 8 * MAXT256;    // 568  (divisible by 8: chunk 71)

DEV u16 f2bf(float f) {          // RTNE float -> bf16 bits
  uint32_t u = __builtin_bit_cast(uint32_t, f);
  u += 0x7fffu + ((u >> 16) & 1u);
  return (u16)(u >> 16);
}

DEV void gload16(const void* g, void* l) {
  __builtin_amdgcn_global_load_lds((const __attribute__((address_space(1))) void*)g,
                                   (__attribute__((address_space(3))) void*)l, 16, 0, 0);
}

DEV bf16x8 ldfrag(const char* p) { return __builtin_bit_cast(bf16x8, *(const u16x8*)p); }

DEV f32x4 MFMA(bf16x8 a, bf16x8 b, f32x4 c) {
  return __builtin_amdgcn_mfma_f32_16x16x32_bf16(a, b, c, 0, 0, 0);
}

// ---- routing ----
// meta[0..7]=counts, [8..15]=cursor, [16..23]=padded offsets, [24]=total rows,
// [25]=n tiles256, [32..103)=tile table (expert | mtile<<8)
__global__ void k_init(int* meta, int* slot_token) {
  const int i = blockIdx.x * 256 + threadIdx.x;
  if (i < 32) meta[i] = 0;
  if (i < MAXS) slot_token[i] = -1;
}

__global__ void k_count(const int* __restrict__ eidx, int* meta) {
  const int p = blockIdx.x * 256 + threadIdx.x;
  if (p < NP) atomicAdd(&meta[eidx[p] & 7], 1);
}

__global__ void k_scan(int* meta) {
  if (threadIdx.x == 0 && blockIdx.x == 0) {
    int off = 0, t2 = 0;
    for (int e = 0; e < NE; ++e) {
      meta[16 + e] = off;
      const int c = meta[e];
      off += ((c + 127) >> 7) << 7;
      for (int mt = 0; mt * 256 < c; ++mt) meta[32 + t2++] = e | (mt << 8);
    }
    meta[24] = off;
    meta[25] = t2;
  }
}

__global__ void k_fill(const int* __restrict__ eidx, const float* __restrict__ ew,
                       int* meta, int* slot_token, float* slot_weight, int* pair_slot) {
  const int p = blockIdx.x * 256 + threadIdx.x;
  if (p < NP) {
    const int e = eidx[p] & 7;
    const int pos = meta[16 + e] + atomicAdd(&meta[8 + e], 1);
    slot_token[pos]  = p >> 1;
    slot_weight[pos] = ew[p];
    pair_slot[p] = pos;
  }
}

// gather selected token rows -> bf16, zeros for padding/slack slots
__global__ void k_gather(const float* __restrict__ x, const int* __restrict__ slot_token,
                         u16* __restrict__ Xg) {
  const int s = blockIdx.x;
  const int tok = slot_token[s];
  const int c = threadIdx.x * 4;
  alignas(8) u16 b[4] = {0, 0, 0, 0};
  if (tok >= 0) {
    const float4 v = *reinterpret_cast<const float4*>(x + (size_t)tok * DM + c);
    b[0] = f2bf(v.x); b[1] = f2bf(v.y); b[2] = f2bf(v.z); b[3] = f2bf(v.w);
  }
  *reinterpret_cast<uint2*>(Xg + (size_t)s * DM + c) = *reinterpret_cast<const uint2*>(b);
}

// src [K][N] fp32 -> dst [N][K] bf16
__global__ void k_transpose(const float* __restrict__ src, u16* __restrict__ dst, int K, int N) {
  const size_t mo = (size_t)blockIdx.z * K * N;
  const float* s = src + mo;
  u16* d = dst + mo;
  const int n0 = blockIdx.x * 64, k0 = blockIdx.y * 64;
  __shared__ u16 tile[64][72];
  const int t = threadIdx.x;
  const int r = t >> 4, cb = (t & 15) * 4;
#pragma unroll
  for (int it = 0; it < 4; ++it) {
    const float4 v = *reinterpret_cast<const float4*>(s + (size_t)(k0 + r + it * 16) * N + n0 + cb);
    tile[r + it * 16][cb + 0] = f2bf(v.x);
    tile[r + it * 16][cb + 1] = f2bf(v.y);
    tile[r + it * 16][cb + 2] = f2bf(v.z);
    tile[r + it * 16][cb + 3] = f2bf(v.w);
  }
  __syncthreads();
  const int nl = t >> 2, ks = (t & 3) * 16;
  alignas(16) u16 vals[16];
#pragma unroll
  for (int j = 0; j < 16; ++j) vals[j] = tile[ks + j][nl];
  u16* dp = d + (size_t)(n0 + nl) * K + k0 + ks;
  *reinterpret_cast<uint4*>(dp)     = *reinterpret_cast<const uint4*>(vals);
  *reinterpret_cast<uint4*>(dp + 8) = *reinterpret_cast<const uint4*>(vals + 8);
}

// ============ 8-phase GEMM1: H = silu(Xg@w1T) * (Xg@w2T) ============
// BM=256, BN=128 dual, BK=64, 8 waves (2Mx4N), acc 128; LDS 2x64KB, XOR swizzle
// 1D grid + bijective XCD-chunked swizzle (T1): each XCD owns consecutive m-tiles
__global__ __launch_bounds__(512, 2)
void k_gemm1(const u16* __restrict__ Xg, const u16* __restrict__ w1T, const u16* __restrict__ w2T,
             u16* __restrict__ H, const int* __restrict__ meta) {
  const int bid = blockIdx.x;
  const int rem = (bid & 7) * (NWG1 / 8) + (bid >> 3);   // XCD-chunked remap
  const int ti = rem >> 4;
  if (ti >= meta[25]) return;
  const int n0 = (rem & 15) * 128;
  const int ent = meta[32 + ti];
  const int e = ent & 255, mt = ent >> 8;
  const int base = meta[16 + e];
  const int cntp = meta[17 + e] - base;   // this expert's 128-padded row count

  __shared__ __align__(16) char sm[2][65536];

  const int tid = threadIdx.x;
  const int lane = tid & 63;
  const int w = tid >> 6;                  // 0..7
  const int wr = w >> 2, wc = w & 3;       // 2M x 4N
  const int lrow = lane & 15, lk = lane >> 4;
  const int SX = lrow & 7;
  int cofs[2];
  cofs[0] = ((0 * 4 + lk) ^ SX) * 16;
  cofs[1] = ((1 * 4 + lk) ^ SX) * 16;
  const int Abase  = (wr * 128 + lrow) * 128;
  const int B1base = 32768 + (wc * 32 + lrow) * 128;
  const int B2base = B1base + 16384;

  const int srow8 = tid >> 3;
  const int scolw = ((tid & 7) ^ (srow8 & 7)) * 16;   // pre-swizzled source col

  const char* AgT = (const char*)(Xg + (size_t)(base + mt * 256) * DM) + (size_t)srow8 * 2048 + scolw;
  const char* B1T = (const char*)(w1T + ((size_t)e * DF + n0) * DM)    + (size_t)srow8 * 2048 + scolw;
  const char* B2T = (const char*)(w2T + ((size_t)e * DF + n0) * DM)    + (size_t)srow8 * 2048 + scolw;

  f32x4 acc1[8][2] = {};
  f32x4 acc2[8][2] = {};

  auto SP = [&](char* d, size_t kb, int q) {
    switch (q) {
      case 0: gload16(AgT + kb,          d + tid * 16);
              gload16(AgT + 131072 + kb, d + 8192  + tid * 16); break;
      case 1: gload16(AgT + 262144 + kb, d + 16384 + tid * 16);
              gload16(AgT + 393216 + kb, d + 24576 + tid * 16); break;
      case 2: gload16(B1T + kb,          d + 32768 + tid * 16);
              gload16(B1T + 131072 + kb, d + 40960 + tid * 16); break;
      case 3: gload16(B2T + kb,          d + 49152 + tid * 16);
              gload16(B2T + 131072 + kb, d + 57344 + tid * 16); break;
    }
  };

  bf16x8 b1f[2][2], b2f[2][2];

  auto LDA4 = [&](const char* s, int mh, int ks, bf16x8* a) {
#pragma unroll
    for (int j = 0; j < 4; ++j)
      a[j] = ldfrag(s + Abase + mh * 8192 + j * 2048 + cofs[ks]);
  };
  auto MF16 = [&](int mh, int ks, const bf16x8* a) {
    __builtin_amdgcn_s_setprio(1);
#pragma unroll
    for (int j = 0; j < 4; ++j)
#pragma unroll
      for (int n = 0; n < 2; ++n) {
        acc1[mh * 4 + j][n] = MFMA(a[j], b1f[n][ks], acc1[mh * 4 + j][n]);
        acc2[mh * 4 + j][n] = MFMA(a[j], b2f[n][ks], acc2[mh * 4 + j][n]);
      }
    __builtin_amdgcn_s_setprio(0);
  };

  SP(sm[0], 0, 0); SP(sm[0], 0, 1); SP(sm[0], 0, 2); SP(sm[0], 0, 3);   // tile 0

  for (int kt = 0; kt < 16; ++kt) {
    const char* s = sm[kt & 1];
    char* d = sm[(kt + 1) & 1];
    const size_t kbn = (size_t)((kt + 1 < 16) ? kt + 1 : 15) * 128;
    bf16x8 a[4];

    SP(d, kbn, 0);
    asm volatile("s_waitcnt vmcnt(2)" ::: "memory");
    __builtin_amdgcn_s_barrier();
#pragma unroll
    for (int n = 0; n < 2; ++n)
#pragma unroll
      for (int s2 = 0; s2 < 2; ++s2) {
        b1f[n][s2] = ldfrag(s + B1base + n * 2048 + cofs[s2]);
        b2f[n][s2] = ldfrag(s + B2base + n * 2048 + cofs[s2]);
      }
    LDA4(s, 0, 0, a);
    MF16(0, 0, a);
    __builtin_amdgcn_s_barrier();

    LDA4(s, 1, 0, a);
    SP(d, kbn, 1);
    __builtin_amdgcn_s_barrier();
    MF16(1, 0, a);
    __builtin_amdgcn_s_barrier();

    LDA4(s, 0, 1, a);
    SP(d, kbn, 2);
    __builtin_amdgcn_s_barrier();
    MF16(0, 1, a);
    __builtin_amdgcn_s_barrier();

    LDA4(s, 1, 1, a);
    SP(d, kbn, 3);
    __builtin_amdgcn_s_barrier();
    MF16(1, 1, a);
    __builtin_amdgcn_s_barrier();
  }

  u16* Hrow = H + (size_t)(base + mt * 256) * DF + n0;
#pragma unroll
  for (int m = 0; m < 8; ++m)
#pragma unroll
    for (int r = 0; r < 4; ++r) {
      const int rloc = wr * 128 + m * 16 + lk * 4 + r;
      if (mt * 256 + rloc >= cntp) continue;   // expert-boundary mask
      u16* hp = Hrow + (size_t)rloc * DF + wc * 32 + lrow;
#pragma unroll
      for (int n = 0; n < 2; ++n) {
        const float h1 = acc1[m][n][r], h2 = acc2[m][n][r];
        const float sv = h1 / (1.f + __expf(-h1)) * h2;   // silu(h1)*h2
        hp[n * 16] = f2bf(sv);
      }
    }
}

// ============ 8-phase GEMM2: O_slot = wgt * (H @ w3T) ============
// BM=256, BN=128 single, BK=64, 8 waves (2Mx4N), acc 64; LDS 2x48KB
// 568 blocks (2.2 rounds, no tail cliff) + XCD-chunked swizzle
__global__ __launch_bounds__(512, 2)
void k_gemm2(const u16* __restrict__ H, const u16* __restrict__ w3T, const int* __restrict__ meta,
             const float* __restrict__ slot_weight, u16* __restrict__ O) {
  const int bid = blockIdx.x;
  const int rem = (bid & 7) * (NWG2 / 8) + (bid >> 3);
  const int ti = rem >> 3;
  if (ti >= meta[25]) return;
  const int n0 = (rem & 7) * 128;
  const int ent = meta[32 + ti];
  const int e = ent & 255, mt = ent >> 8;
  const int base = meta[16 + e];
  const int cntp = meta[17 + e] - base;

  __shared__ __align__(16) char sm[2][49152];

  const int tid = threadIdx.x;
  const int lane = tid & 63;
  const int w = tid >> 6;
  const int wr = w >> 2, wc = w & 3;       // 2M x 4N
  const int lrow = lane & 15, lk = lane >> 4;
  const int SX = lrow & 7;
  int cofs[2];
  cofs[0] = ((0 * 4 + lk) ^ SX) * 16;
  cofs[1] = ((1 * 4 + lk) ^ SX) * 16;
  const int Abase = (wr * 128 + lrow) * 128;
  const int Bbase = 32768 + (wc * 32 + lrow) * 128;

  const int srow8 = tid >> 3;
  const int scolw = ((tid & 7) ^ (srow8 & 7)) * 16;

  const char* AgT = (const char*)(H + (size_t)(base + mt * 256) * DF) + (size_t)srow8 * 4096 + scolw;
  const char* BgT = (const char*)(w3T + ((size_t)e * DM + n0) * DF)   + (size_t)srow8 * 4096 + scolw;

  f32x4 acc[8][2] = {};

  auto SP = [&](char* d, size_t kb, int q) {   // 6 loads/thread/tile: A=4, B=2
    switch (q) {
      case 0: gload16(AgT + kb,          d + tid * 16);
              gload16(AgT + 262144 + kb, d + 8192  + tid * 16); break;
      case 1: gload16(AgT + 524288 + kb, d + 16384 + tid * 16);
              gload16(AgT + 786432 + kb, d + 24576 + tid * 16); break;
      case 2: gload16(BgT + kb,          d + 32768 + tid * 16);
              gload16(BgT + 262144 + kb, d + 40960 + tid * 16); break;
    }
  };

  bf16x8 bf[2][2];

  auto LDA4 = [&](const char* s, int mh, int ks, bf16x8* a) {
#pragma unroll
    for (int j = 0; j < 4; ++j)
      a[j] = ldfrag(s + Abase + mh * 8192 + j * 2048 + cofs[ks]);
  };
  auto MF8 = [&](int mh, int ks, const bf16x8* a) {
    __builtin_amdgcn_s_setprio(1);
#pragma unroll
    for (int j = 0; j < 4; ++j)
#pragma unroll
      for (int n = 0; n < 2; ++n)
        acc[mh * 4 + j][n] = MFMA(a[j], bf[n][ks], acc[mh * 4 + j][n]);
    __builtin_amdgcn_s_setprio(0);
  };

  SP(sm[0], 0, 0); SP(sm[0], 0, 1); SP(sm[0], 0, 2);

  for (int kt = 0; kt < 32; ++kt) {
    const char* s = sm[kt & 1];
    char* d = sm[(kt + 1) & 1];
    const size_t kbn = (size_t)((kt + 1 < 32) ? kt + 1 : 31) * 128;
    bf16x8 a[4];

    SP(d, kbn, 0);
    asm volatile("s_waitcnt vmcnt(2)" ::: "memory");
    __builtin_amdgcn_s_barrier();
#pragma unroll
    for (int n = 0; n < 2; ++n)
#pragma unroll
      for (int s2 = 0; s2 < 2; ++s2)
        bf[n][s2] = ldfrag(s + Bbase + n * 2048 + cofs[s2]);
    LDA4(s, 0, 0, a);
    MF8(0, 0, a);
    __builtin_amdgcn_s_barrier();

    LDA4(s, 1, 0, a);
    SP(d, kbn, 1);
    __builtin_amdgcn_s_barrier();
    MF8(1, 0, a);
    __builtin_amdgcn_s_barrier();

    LDA4(s, 0, 1, a);
    SP(d, kbn, 2);
    __builtin_amdgcn_s_barrier();
    MF8(0, 1, a);
    __builtin_amdgcn_s_barrier();

    LDA4(s, 1, 1, a);
    __builtin_amdgcn_s_barrier();
    MF8(1, 1, a);
    __builtin_amdgcn_s_barrier();
  }

  const int sb = base + mt * 256;
#pragma unroll
  for (int m = 0; m < 8; ++m)
#pragma unroll
    for (int r = 0; r < 4; ++r) {
      const int rloc = wr * 128 + m * 16 + lk * 4 + r;
      if (mt * 256 + rloc >= cntp) continue;
      const float wgt = slot_weight[sb + rloc];
      u16* op = O + (size_t)(sb + rloc) * DM + n0 + wc * 32 + lrow;
#pragma unroll
      for (int n = 0; n < 2; ++n)
        op[n * 16] = f2bf(wgt * acc[m][n][r]);
    }
}

// out[t] = O[slot(2t)] + O[slot(2t+1)]
__global__ void k_combine(const u16* __restrict__ O, const int* __restrict__ pair_slot,
                          float* __restrict__ out) {
  const int t = blockIdx.x;
  const int c = threadIdx.x * 4;
  const int sa = pair_slot[2 * t], sb = pair_slot[2 * t + 1];
  const uint2 va = *reinterpret_cast<const uint2*>(O + (size_t)sa * DM + c);
  const uint2 vb = *reinterpret_cast<const uint2*>(O + (size_t)sb * DM + c);
  float4 r;
  r.x = __builtin_bit_cast(float, va.x << 16)          + __builtin_bit_cast(float, vb.x << 16);
  r.y = __builtin_bit_cast(float, va.x & 0xffff0000u)  + __builtin_bit_cast(float, vb.x & 0xffff0000u);
  r.z = __builtin_bit_cast(float, va.y << 16)          + __builtin_bit_cast(float, vb.y << 16);
  r.w = __builtin_bit_cast(float, va.y & 0xffff0000u)  + __builtin_bit_cast(float, vb.y & 0xffff0000u);
  *reinterpret_cast<float4*>(out + (size_t)t * DM + c) = r;
}

extern "C" void kernel_launch(void* const* d_in, const int* in_sizes, int n_in,
                              void* d_out, int out_size, void* d_ws, size_t ws_size,
                              hipStream_t stream) {
  const float* x  = (const float*)d_in[0];
  const int* eidx = (const int*)d_in[1];
  const float* ew = (const float*)d_in[2];
  const float* w1 = (const float*)d_in[3];
  const float* w2 = (const float*)d_in[4];
  const float* w3 = (const float*)d_in[5];
  float* out = (float*)d_out;
  char* ws = (char*)d_ws;

  int* meta          = (int*)ws;                           // 1 KB
  int* pair_slot     = (int*)(ws + 1024);                  // 64 KB
  int* slot_token    = (int*)(ws + 1024 + 65536);
  float* slot_weight = (float*)(ws + 1024 + 65536 + (size_t)MAXS * 4);
  size_t off = 1024 + 65536 + (size_t)MAXS * 8;
  u16* Xg  = (u16*)(ws + off); off += (size_t)MAXS * DM * 2;   // reused as O_slot
  u16* w1T = (u16*)(ws + off); off += (size_t)NE * DM * DF * 2;
  u16* w2T = (u16*)(ws + off); off += (size_t)NE * DM * DF * 2;
  u16* w3T = (u16*)(ws + off); off += (size_t)NE * DM * DF * 2;
  u16* H   = (u16*)(ws + off);  // MAXS * DF * 2 bytes
  u16* O   = Xg;                // Xg is dead after k_gemm1

  k_init<<<(MAXS + 255) / 256, 256, 0, stream>>>(meta, slot_token);
  k_count<<<NP / 256, 256, 0, stream>>>(eidx, meta);
  k_scan<<<1, 64, 0, stream>>>(meta);
  k_fill<<<NP / 256, 256, 0, stream>>>(eidx, ew, meta, slot_token, slot_weight, pair_slot);
  k_gather<<<MAXS, 256, 0, stream>>>(x, slot_token, Xg);
  k_transpose<<<dim3(DF / 64, DM / 64, NE), 256, 0, stream>>>(w1, w1T, DM, DF);
  k_transpose<<<dim3(DF / 64, DM / 64, NE), 256, 0, stream>>>(w2, w2T, DM, DF);
  k_transpose<<<dim3(DM / 64, DF / 64, NE), 256, 0, stream>>>(w3, w3T, DF, DM);
  k_gemm1<<<NWG1, 512, 0, stream>>>(Xg, w1T, w2T, H, meta);
  k_gemm2<<<NWG2, 512, 0, stream>>>(H, w3T, meta, slot_weight, O);
  k_combine<<<NT, 256, 0, stream>>>(O, pair_slot, out);
}